// Round 1
// baseline (401.840 us; speedup 1.0000x reference)
//
#include <hip/hip_runtime.h>

// MaskedGNN on MI355X — round 1: correct fp32, LDS-staged-weight tiled GEMMs.
// H=128, N=64, B=128, L=3, F=7, E=64, LAT=128.

constexpr int Hd = 128;
constexpr int Nn = 64;
constexpr int Fd = 7;
constexpr int Ed = 64;
constexpr float EPS = 1e-5f;
constexpr float NEGI = -1e9f;

// ---------- device helpers ----------

__device__ __forceinline__ void g2s(float* dst, const float* __restrict__ src,
                                    int nfloats, int tid, int nthr) {
  const float4* s4 = (const float4*)src;
  float4* d4 = (float4*)dst;
  int n4 = nfloats >> 2;
  for (int i = tid; i < n4; i += nthr) d4[i] = s4[i];
}

// acc[4][4] += A[r0..r0+3][0..K) @ W[0..K)[c4..c4+3]
// sA: LDS tile, row stride LDA floats (16B-aligned rows). sW: LDS [K][128].
template<int K, int LDA>
__device__ __forceinline__ void gemm_tile(const float* sA, const float* sW,
                                          int r0, int c4, float acc[4][4]) {
#pragma unroll 4
  for (int h = 0; h < K; h += 4) {
    float4 b0 = *(const float4*)(sW + (h + 0) * Hd + c4);
    float4 b1 = *(const float4*)(sW + (h + 1) * Hd + c4);
    float4 b2 = *(const float4*)(sW + (h + 2) * Hd + c4);
    float4 b3 = *(const float4*)(sW + (h + 3) * Hd + c4);
#pragma unroll
    for (int r = 0; r < 4; ++r) {
      float4 a = *(const float4*)(sA + (r0 + r) * LDA + h);
      acc[r][0] = fmaf(a.w, b3.x, fmaf(a.z, b2.x, fmaf(a.y, b1.x, fmaf(a.x, b0.x, acc[r][0]))));
      acc[r][1] = fmaf(a.w, b3.y, fmaf(a.z, b2.y, fmaf(a.y, b1.y, fmaf(a.x, b0.y, acc[r][1]))));
      acc[r][2] = fmaf(a.w, b3.z, fmaf(a.z, b2.z, fmaf(a.y, b1.z, fmaf(a.x, b0.z, acc[r][2]))));
      acc[r][3] = fmaf(a.w, b3.w, fmaf(a.z, b2.w, fmaf(a.y, b1.w, fmaf(a.x, b0.w, acc[r][3]))));
    }
  }
}

__device__ __forceinline__ void store_acc(float* dst, int ldd, int r0, int c4,
                                          const float acc[4][4], const float* bias) {
  float4 bv = bias ? *(const float4*)(bias + c4) : make_float4(0.f, 0.f, 0.f, 0.f);
#pragma unroll
  for (int r = 0; r < 4; ++r) {
    float4 o;
    o.x = acc[r][0] + bv.x;
    o.y = acc[r][1] + bv.y;
    o.z = acc[r][2] + bv.z;
    o.w = acc[r][3] + bv.w;
    *(float4*)(dst + (r0 + r) * ldd + c4) = o;
  }
}

// LN stats over a 32x128 LDS tile (stride 128), 256 threads.
// mv[0..31]=mean, mv[32..63]=rstd. red: 512 floats scratch.
__device__ __forceinline__ void ln_stats(const float* tile, float* red, float* mv, int tid) {
  int r = tid >> 3, s = tid & 7;
  const float* p = tile + r * Hd + s;  // strided cols: banks spread (8-way worst)
  float sum = 0.f, sq = 0.f;
#pragma unroll
  for (int k = 0; k < 16; ++k) { float v = p[k * 8]; sum += v; sq += v * v; }
  red[tid] = sum;
  red[256 + tid] = sq;
  __syncthreads();
  if (tid < 32) {
    float S = 0.f, Q = 0.f;
#pragma unroll
    for (int k = 0; k < 8; ++k) { S += red[tid * 8 + k]; Q += red[256 + tid * 8 + k]; }
    float m = S * (1.f / 128.f);
    float var = Q * (1.f / 128.f) - m * m;
    mv[tid] = m;
    mv[32 + tid] = rsqrtf(fmaxf(var, 0.f) + EPS);
  }
  __syncthreads();
}

// ---------- kernels ----------

// Encoder: x = relu(LN(relu(LN(emb@W1+b1))@W2+b2)) * mask   [8192 rows]
__global__ __launch_bounds__(256) void enc_kernel(
    const float* __restrict__ emb, const float* __restrict__ mask,
    const float* __restrict__ W1, const float* __restrict__ b1,
    const float* __restrict__ g1, const float* __restrict__ B1,
    const float* __restrict__ W2, const float* __restrict__ b2,
    const float* __restrict__ g2, const float* __restrict__ B2,
    float* __restrict__ xout) {
  __shared__ alignas(16) float s_W[Hd * Hd];
  __shared__ alignas(16) float s_A[32 * Ed];
  __shared__ alignas(16) float s_H[32 * Hd];
  __shared__ alignas(16) float s_O[32 * Hd];
  __shared__ float s_red[512];
  __shared__ float s_mv[64];
  int tid = threadIdx.x;
  int row0 = blockIdx.x * 32;
  int c4 = (tid & 31) * 4, r0 = (tid >> 5) * 4;

  g2s(s_A, emb + row0 * Ed, 32 * Ed, tid, 256);
  g2s(s_W, W1, Ed * Hd, tid, 256);
  __syncthreads();

  {
    float acc[4][4] = {};
    gemm_tile<Ed, Ed>(s_A, s_W, r0, c4, acc);
    store_acc(s_H, Hd, r0, c4, acc, b1);
  }
  __syncthreads();
  ln_stats(s_H, s_red, s_mv, tid);
  for (int idx = tid; idx < 32 * Hd; idx += 256) {
    int r = idx >> 7, c = idx & 127;
    float v = (s_H[idx] - s_mv[r]) * s_mv[32 + r] * g1[c] + B1[c];
    s_H[idx] = fmaxf(v, 0.f);
  }
  __syncthreads();

  g2s(s_W, W2, Hd * Hd, tid, 256);
  __syncthreads();
  {
    float acc[4][4] = {};
    gemm_tile<Hd, Hd>(s_H, s_W, r0, c4, acc);
    store_acc(s_O, Hd, r0, c4, acc, b2);
  }
  __syncthreads();
  ln_stats(s_O, s_red, s_mv, tid);
  for (int idx = tid; idx < 32 * Hd; idx += 256) {
    int r = idx >> 7, c = idx & 127;
    float v = (s_O[idx] - s_mv[r]) * s_mv[32 + r] * g2[c] + B2[c];
    v = fmaxf(v, 0.f) * mask[row0 + r];
    xout[row0 * Hd + idx] = v;
  }
}

// Per layer: v = x@Wv+bv ; hq = (x@Wq+bq)@We1a ; hk = (x@Wk+bk)@We1b + be1
__global__ __launch_bounds__(256) void qkv_kernel(
    const float* __restrict__ x,
    const float* __restrict__ Wq, const float* __restrict__ bq,
    const float* __restrict__ Wk, const float* __restrict__ bk,
    const float* __restrict__ Wv, const float* __restrict__ bv,
    const float* __restrict__ We1, const float* __restrict__ be1,
    float* __restrict__ vout, float* __restrict__ hqout, float* __restrict__ hkout) {
  __shared__ alignas(16) float s_W[Hd * Hd];
  __shared__ alignas(16) float s_X[32 * Hd];
  __shared__ alignas(16) float s_Q[32 * Hd];
  __shared__ alignas(16) float s_K[32 * Hd];
  int tid = threadIdx.x;
  int row0 = blockIdx.x * 32;
  int c4 = (tid & 31) * 4, r0 = (tid >> 5) * 4;

  g2s(s_X, x + row0 * Hd, 32 * Hd, tid, 256);
  g2s(s_W, Wq, Hd * Hd, tid, 256);
  __syncthreads();
  { float acc[4][4] = {}; gemm_tile<Hd, Hd>(s_X, s_W, r0, c4, acc); store_acc(s_Q, Hd, r0, c4, acc, bq); }
  __syncthreads();

  g2s(s_W, Wk, Hd * Hd, tid, 256);
  __syncthreads();
  { float acc[4][4] = {}; gemm_tile<Hd, Hd>(s_X, s_W, r0, c4, acc); store_acc(s_K, Hd, r0, c4, acc, bk); }
  __syncthreads();

  g2s(s_W, Wv, Hd * Hd, tid, 256);
  __syncthreads();
  { float acc[4][4] = {}; gemm_tile<Hd, Hd>(s_X, s_W, r0, c4, acc); store_acc(vout + row0 * Hd, Hd, r0, c4, acc, bv); }
  __syncthreads();

  g2s(s_W, We1, Hd * Hd, tid, 256);
  __syncthreads();
  { float acc[4][4] = {}; gemm_tile<Hd, Hd>(s_Q, s_W, r0, c4, acc); store_acc(hqout + row0 * Hd, Hd, r0, c4, acc, nullptr); }
  __syncthreads();

  g2s(s_W, We1 + Hd * Hd, Hd * Hd, tid, 256);
  __syncthreads();
  { float acc[4][4] = {}; gemm_tile<Hd, Hd>(s_K, s_W, r0, c4, acc); store_acc(hkout + row0 * Hd, Hd, r0, c4, acc, be1); }
}

// scores + masked softmax -> attn.  grid: (b, i-chunk of 16), 256 thr (4 waves).
__global__ __launch_bounds__(256) void score_kernel(
    const float* __restrict__ hq, const float* __restrict__ hk,
    const float* __restrict__ mask, const float* __restrict__ We2,
    const float* __restrict__ be2p, float* __restrict__ attn) {
  __shared__ alignas(16) float s_hk[Nn * 129];   // +1 pad: lane-j reads conflict-free
  __shared__ alignas(16) float s_hq[16 * Hd];
  __shared__ float s_w2[Hd];
  __shared__ float s_mk[Nn];
  int tid = threadIdx.x;
  int b = blockIdx.x >> 2;
  int i0 = (blockIdx.x & 3) << 4;

  const float* hkb = hk + b * Nn * Hd;
  for (int idx = tid; idx < Nn * Hd; idx += 256) {
    int j = idx >> 7, c = idx & 127;
    s_hk[j * 129 + c] = hkb[idx];
  }
  g2s(s_hq, hq + (b * Nn + i0) * Hd, 16 * Hd, tid, 256);
  if (tid < Hd) s_w2[tid] = We2[tid];
  if (tid < Nn) s_mk[tid] = mask[b * Nn + tid];
  __syncthreads();

  float be2v = be2p[0];
  int w = tid >> 6, j = tid & 63;
  float mj = s_mk[j];
  const float* hkj = s_hk + j * 129;
#pragma unroll
  for (int k = 0; k < 4; ++k) {
    int il = w * 4 + k;
    const float* hqr = s_hq + il * Hd;
    float s0 = 0.f, s1 = 0.f, s2 = 0.f, s3 = 0.f;
#pragma unroll 8
    for (int h = 0; h < Hd; h += 4) {
      s0 += fmaxf(hqr[h + 0] + hkj[h + 0], 0.f) * s_w2[h + 0];
      s1 += fmaxf(hqr[h + 1] + hkj[h + 1], 0.f) * s_w2[h + 1];
      s2 += fmaxf(hqr[h + 2] + hkj[h + 2], 0.f) * s_w2[h + 2];
      s3 += fmaxf(hqr[h + 3] + hkj[h + 3], 0.f) * s_w2[h + 3];
    }
    float sc = (s0 + s1) + (s2 + s3) + be2v;
    float m2 = s_mk[i0 + il] * mj;
    sc = (m2 > 0.f) ? sc : NEGI;
    float mx = sc;
#pragma unroll
    for (int off = 32; off >= 1; off >>= 1) mx = fmaxf(mx, __shfl_xor(mx, off));
    float p = __expf(sc - mx);
    float sm = p;
#pragma unroll
    for (int off = 32; off >= 1; off >>= 1) sm += __shfl_xor(sm, off);
    attn[(b * Nn + i0 + il) * Nn + j] = p / sm * m2;
  }
}

// agg = attn@v ; x = relu(LN(agg@Wo+bo)) * mask.  grid: (b, i-half of 32), 256 thr.
__global__ __launch_bounds__(256) void agg_kernel(
    const float* __restrict__ attn, const float* __restrict__ v,
    const float* __restrict__ Wo, const float* __restrict__ bo,
    const float* __restrict__ og, const float* __restrict__ oB,
    const float* __restrict__ mask, float* __restrict__ xout) {
  __shared__ alignas(16) float s_W[Hd * Hd];
  __shared__ alignas(16) float s_V[Nn * Hd];
  __shared__ alignas(16) float s_att[32 * Nn];
  __shared__ alignas(16) float s_T[32 * Hd];
  __shared__ float s_red[512];
  __shared__ float s_mv[64];
  int tid = threadIdx.x;
  int b = blockIdx.x >> 1;
  int i0 = (blockIdx.x & 1) * 32;
  int c4 = (tid & 31) * 4, r0 = (tid >> 5) * 4;

  g2s(s_W, Wo, Hd * Hd, tid, 256);
  g2s(s_V, v + b * Nn * Hd, Nn * Hd, tid, 256);
  g2s(s_att, attn + (b * Nn + i0) * Nn, 32 * Nn, tid, 256);
  __syncthreads();

  float acc[4][4] = {};
  gemm_tile<Nn, Nn>(s_att, s_V, r0, c4, acc);
  store_acc(s_T, Hd, r0, c4, acc, nullptr);
  __syncthreads();

  float acc2[4][4] = {};
  gemm_tile<Hd, Hd>(s_T, s_W, r0, c4, acc2);
  __syncthreads();                    // all reads of s_T done before overwrite
  store_acc(s_T, Hd, r0, c4, acc2, bo);
  __syncthreads();

  ln_stats(s_T, s_red, s_mv, tid);
  int rowg0 = b * Nn + i0;
  for (int idx = tid; idx < 32 * Hd; idx += 256) {
    int r = idx >> 7, c = idx & 127;
    float val = (s_T[idx] - s_mv[r]) * s_mv[32 + r] * og[c] + oB[c];
    val = fmaxf(val, 0.f) * mask[rowg0 + r];
    xout[rowg0 * Hd + idx] = val;
  }
}

// 128-wide LN across a 128-thread block (2 waves). red: 4 floats.
__device__ __forceinline__ float ln128(float val, float g, float be, int t, float* red) {
  float s = val, q = val * val;
#pragma unroll
  for (int off = 32; off >= 1; off >>= 1) {
    s += __shfl_xor(s, off);
    q += __shfl_xor(q, off);
  }
  if ((t & 63) == 0) { red[(t >> 6) * 2] = s; red[(t >> 6) * 2 + 1] = q; }
  __syncthreads();
  float S = red[0] + red[2], Q = red[1] + red[3];
  __syncthreads();
  float m = S * (1.f / 128.f);
  float var = Q * (1.f / 128.f) - m * m;
  float r = rsqrtf(fmaxf(var, 0.f) + EPS);
  return (val - m) * r * g + be;
}

// masked-mean pool + decoder MLP. grid 128 blocks x 128 thr.
__global__ __launch_bounds__(128) void dec_kernel(
    const float* __restrict__ bf, const float* __restrict__ x, const float* __restrict__ mask,
    const float* __restrict__ dW1, const float* __restrict__ db1,
    const float* __restrict__ dg1, const float* __restrict__ dB1,
    const float* __restrict__ dW2, const float* __restrict__ db2,
    const float* __restrict__ dg2, const float* __restrict__ dB2,
    const float* __restrict__ dW3, const float* __restrict__ db3,
    float* __restrict__ out) {
  __shared__ float s_d[Fd + Hd + 1];
  __shared__ float s_z[Hd];
  __shared__ float red[4];
  __shared__ float s_mk[Nn];
  int b = blockIdx.x, t = threadIdx.x;
  if (t < Nn) s_mk[t] = mask[b * Nn + t];
  __syncthreads();
  float den = 0.f;
#pragma unroll
  for (int i = 0; i < Nn; ++i) den += s_mk[i];
  den = fmaxf(den, 1.f);
  float pooled = 0.f;
  const float* xb = x + b * Nn * Hd;
  for (int i = 0; i < Nn; ++i) pooled += xb[i * Hd + t];
  pooled /= den;
  if (t < Fd) s_d[t] = bf[b * Fd + t];
  s_d[Fd + t] = pooled;
  __syncthreads();

  float z = db1[t];
  for (int k = 0; k < Fd + Hd; ++k) z = fmaf(s_d[k], dW1[k * Hd + t], z);
  z = ln128(z, dg1[t], dB1[t], t, red);
  z = fmaxf(z, 0.f);
  s_z[t] = z;
  __syncthreads();

  float z2 = db2[t];
  for (int k = 0; k < Hd; ++k) z2 = fmaf(s_z[k], dW2[k * Hd + t], z2);
  z2 = ln128(z2, dg2[t], dB2[t], t, red);  // ln128's syncs fence the s_z reads
  z2 = fmaxf(z2, 0.f);
  s_z[t] = z2;
  __syncthreads();

  if (t < Fd) {
    float o = db3[t];
    for (int k = 0; k < Hd; ++k) o = fmaf(s_z[k], dW3[k * Fd + t], o);
    out[b * Fd + t] = o;
  }
}

// ---------- host ----------

extern "C" void kernel_launch(void* const* d_in, const int* in_sizes, int n_in,
                              void* d_out, int out_size, void* d_ws, size_t ws_size,
                              hipStream_t stream) {
  const float* bf   = (const float*)d_in[0];
  const float* emb  = (const float*)d_in[1];
  const float* mask = (const float*)d_in[2];
  const float* eW1 = (const float*)d_in[3];
  const float* eb1 = (const float*)d_in[4];
  const float* eg1 = (const float*)d_in[5];
  const float* eB1 = (const float*)d_in[6];
  const float* eW2 = (const float*)d_in[7];
  const float* eb2 = (const float*)d_in[8];
  const float* eg2 = (const float*)d_in[9];
  const float* eB2 = (const float*)d_in[10];
  const float* Wq = (const float*)d_in[11];
  const float* bq = (const float*)d_in[12];
  const float* Wk = (const float*)d_in[13];
  const float* bk = (const float*)d_in[14];
  const float* Wv = (const float*)d_in[15];
  const float* bv = (const float*)d_in[16];
  const float* We1 = (const float*)d_in[17];
  const float* be1 = (const float*)d_in[18];
  const float* We2 = (const float*)d_in[19];
  const float* be2 = (const float*)d_in[20];
  const float* Wo = (const float*)d_in[21];
  const float* bo = (const float*)d_in[22];
  const float* og = (const float*)d_in[23];
  const float* oB = (const float*)d_in[24];
  const float* dW1 = (const float*)d_in[25];
  const float* db1 = (const float*)d_in[26];
  const float* dg1 = (const float*)d_in[27];
  const float* dB1 = (const float*)d_in[28];
  const float* dW2 = (const float*)d_in[29];
  const float* db2 = (const float*)d_in[30];
  const float* dg2 = (const float*)d_in[31];
  const float* dB2 = (const float*)d_in[32];
  const float* dW3 = (const float*)d_in[33];
  const float* db3 = (const float*)d_in[34];
  float* out = (float*)d_out;

  float* ws = (float*)d_ws;
  float* x    = ws;                  // 128*64*128 = 1048576 floats
  float* vv   = ws + 1 * 1048576;
  float* hqv  = ws + 2 * 1048576;
  float* hkv  = ws + 3 * 1048576;
  float* attn = ws + 4 * 1048576;    // 128*64*64 = 524288 floats

  enc_kernel<<<256, 256, 0, stream>>>(emb, mask, eW1, eb1, eg1, eB1, eW2, eb2, eg2, eB2, x);
  for (int l = 0; l < 3; ++l) {
    qkv_kernel<<<256, 256, 0, stream>>>(
        x, Wq + l * Hd * Hd, bq + l * Hd, Wk + l * Hd * Hd, bk + l * Hd,
        Wv + l * Hd * Hd, bv + l * Hd, We1 + l * 2 * Hd * Hd, be1 + l * Hd,
        vv, hqv, hkv);
    score_kernel<<<512, 256, 0, stream>>>(hqv, hkv, mask, We2 + l * Hd, be2 + l, attn);
    agg_kernel<<<256, 256, 0, stream>>>(attn, vv, Wo + l * Hd * Hd, bo + l * Hd,
                                        og + l * Hd, oB + l * Hd, mask, x);
  }
  dec_kernel<<<128, 128, 0, stream>>>(bf, x, mask, dW1, db1, dg1, dB1,
                                      dW2, db2, dg2, dB2, dW3, db3, out);
}

// Round 2
// 276.321 us; speedup vs baseline: 1.4543x; 1.4543x over previous
//
#include <hip/hip_runtime.h>

// MaskedGNN on MI355X — round 2: bf16 MFMA GEMMs with pre-packed fragment
// layouts, folded edge-MLP weights, fused score+softmax+agg.
// H=128, N=64, B=128, L=3, F=7, E=64, LAT=128.

constexpr int Hd = 128;
constexpr int Nn = 64;
constexpr int Fd = 7;
constexpr float EPS = 1e-5f;

typedef __bf16 bf16x8 __attribute__((ext_vector_type(8)));
typedef float floatx4 __attribute__((ext_vector_type(4)));

// Fragment layouts (16x16x32 bf16 MFMA, m89/m91-verified):
//   A-frag: lane holds A[m = lane&15][k = (lane>>4)*8 + j], j=0..7
//   B-frag: lane holds B[k = (lane>>4)*8 + j][n = lane&15]
//   C/D:    col = lane&15, row = (lane>>4)*4 + reg
// Packed-A activation layout ("pk"): [mtile][kc][lane][8] bf16, 16B/lane chunks.
// Packed-B weight layout:            [ntile][kc][lane][8] bf16.

// ---------------------------------------------------------------------------
// fold: Wqe[l] = Wq[l]@We1a[l], Wke[l] = Wk[l]@We1b[l]  (fp32)
//       bcat[l] = { bv, bq@We1a, bk@We1b + be1 }
// grid 49 x 256
__global__ __launch_bounds__(256) void fold_kernel(
    const float* __restrict__ Wq, const float* __restrict__ bq,
    const float* __restrict__ Wk, const float* __restrict__ bk,
    const float* __restrict__ bv, const float* __restrict__ We1,
    const float* __restrict__ be1,
    float* __restrict__ folds, float* __restrict__ bcat) {
  int tid = threadIdx.x;
  if (blockIdx.x < 48) {
    __shared__ float sB[128 * 16];
    int job = blockIdx.x >> 3;          // 0..5 : (l, which)
    int cc16 = blockIdx.x & 7;          // col chunk of 16
    int l = job >> 1, w = job & 1;
    const float* A = (w ? Wk : Wq) + l * 16384;
    const float* Bm = We1 + l * 32768 + w * 16384;
    float* out = folds + job * 16384;
    int c0 = cc16 * 16;
    for (int idx = tid; idx < 128 * 16; idx += 256) {
      int kk = idx >> 4, c = idx & 15;
      sB[idx] = Bm[kk * 128 + c0 + c];
    }
    __syncthreads();
    int r = tid >> 1, c8 = (tid & 1) * 8;
    float acc[8] = {};
    const float4* A4 = (const float4*)(A + r * 128);
#pragma unroll 8
    for (int k4 = 0; k4 < 32; ++k4) {
      float4 a = A4[k4];
      float av[4] = {a.x, a.y, a.z, a.w};
#pragma unroll
      for (int kk = 0; kk < 4; ++kk) {
        int k = k4 * 4 + kk;
#pragma unroll
        for (int c = 0; c < 8; ++c) acc[c] += av[kk] * sB[k * 16 + c8 + c];
      }
    }
    for (int c = 0; c < 8; ++c) out[r * 128 + c0 + c8 + c] = acc[c];
  } else {
    // biases
    for (int idx = tid; idx < 3 * 384; idx += 256) {
      int l = idx / 384, c = idx % 384;
      float val;
      if (c < 128) {
        val = bv[l * 128 + c];
      } else if (c < 256) {
        int cc = c - 128;
        float s = 0.f;
        for (int k = 0; k < 128; ++k) s += bq[l * 128 + k] * We1[l * 32768 + k * 128 + cc];
        val = s;
      } else {
        int cc = c - 256;
        float s = be1[l * 128 + cc];
        for (int k = 0; k < 128; ++k) s += bk[l * 128 + k] * We1[l * 32768 + 16384 + k * 128 + cc];
        val = s;
      }
      bcat[l * 384 + c] = val;
    }
  }
}

// ---------------------------------------------------------------------------
// pack: fp32 [K][128] row-major weight -> packed-B bf16 [8][KCH][64][8]
// jobs: 0=encW1(K64) 1=encW2 ; 2+4l+{0,1,2}={Wv,Wqe,Wke}->wcat[l] ; 2+4l+3=Wo[l]
__global__ __launch_bounds__(256) void pack_kernel(
    const float* __restrict__ eW1, const float* __restrict__ eW2,
    const float* __restrict__ Wv, const float* __restrict__ Wo,
    const float* __restrict__ folds,
    __bf16* __restrict__ w1pk, __bf16* __restrict__ w2pk,
    __bf16* __restrict__ wcatpk, __bf16* __restrict__ wopk) {
  __shared__ float sW[128 * 128];
  int tid = threadIdx.x;
  int job = blockIdx.x;
  const float* src;
  __bf16* dst;
  int KCH = 4;
  if (job == 0) { src = eW1; dst = w1pk; KCH = 2; }
  else if (job == 1) { src = eW2; dst = w2pk; }
  else {
    int j = job - 2, l = j >> 2, w = j & 3;
    if (w == 0)      { src = Wv + l * 16384;            dst = wcatpk + l * 49152; }
    else if (w == 1) { src = folds + (2 * l) * 16384;   dst = wcatpk + l * 49152 + 8 * 2048; }
    else if (w == 2) { src = folds + (2 * l + 1) * 16384; dst = wcatpk + l * 49152 + 16 * 2048; }
    else             { src = Wo + l * 16384;            dst = wopk + l * 16384; }
  }
  int K = KCH * 32;
  for (int idx = tid; idx < K * 128; idx += 256) sW[idx] = src[idx];
  __syncthreads();
  int total = 8 * KCH * 64;
  for (int ch = tid; ch < total; ch += 256) {
    int lane = ch & 63;
    int q = ch >> 6;
    int kc = q % KCH, nt = q / KCH;
    int k0 = kc * 32 + (lane >> 4) * 8;
    int n = nt * 16 + (lane & 15);
    bf16x8 pk;
#pragma unroll
    for (int j = 0; j < 8; ++j) pk[j] = (__bf16)sW[(k0 + j) * 128 + n];
    *((bf16x8*)dst + (nt * KCH + kc) * 64 + lane) = pk;
  }
}

// ---------------------------------------------------------------------------
// fused qkv: out = x @ {Wv | Wqe | Wke} + bcat -> v / hq / hk (fp32)
// grid (256, 3) x 128 thr
__global__ __launch_bounds__(128) void gemm_qkv(
    const __bf16* __restrict__ xpk, const __bf16* __restrict__ Bpk,
    const float* __restrict__ bias,
    float* __restrict__ v, float* __restrict__ hq, float* __restrict__ hk) {
  int tid = threadIdx.x, lane = tid & 63, wave = tid >> 6;
  int mtile = blockIdx.x * 2 + wave;
  int nblk = blockIdx.y;
  floatx4 acc[8];
#pragma unroll
  for (int nt = 0; nt < 8; ++nt) acc[nt] = 0;
  const bf16x8* A8 = (const bf16x8*)xpk + (mtile * 4) * 64 + lane;
  const bf16x8* B8 = (const bf16x8*)Bpk + (nblk * 32) * 64 + lane;
#pragma unroll
  for (int kc = 0; kc < 4; ++kc) {
    bf16x8 a = A8[kc * 64];
#pragma unroll
    for (int nt = 0; nt < 8; ++nt) {
      bf16x8 b = B8[(nt * 4 + kc) * 64];
      acc[nt] = __builtin_amdgcn_mfma_f32_16x16x32_bf16(a, b, acc[nt], 0, 0, 0);
    }
  }
  float* outp = (nblk == 0) ? v : ((nblk == 1) ? hq : hk);
  int quad = lane >> 4, cl = lane & 15;
  int rowb = mtile * 16 + quad * 4;
#pragma unroll
  for (int nt = 0; nt < 8; ++nt) {
    int col = nt * 16 + cl;
    float bvv = bias[nblk * 128 + col];
#pragma unroll
    for (int r = 0; r < 4; ++r) outp[(rowb + r) * 128 + col] = acc[nt][r] + bvv;
  }
}

// ---------------------------------------------------------------------------
// GEMM (K = KCH*32, N=128) + bias + LN(g,be) + relu (+mask) ->
//   optional fp32 out + packed-A bf16 out.  grid 256 x 128 thr
template <int KCH, bool AF32, bool MASKED, bool WF32>
__global__ __launch_bounds__(128) void gemm_ln_k(
    const void* __restrict__ Ain, const __bf16* __restrict__ Bpk,
    const float* __restrict__ bias, const float* __restrict__ g,
    const float* __restrict__ be, const float* __restrict__ mask,
    float* __restrict__ outf, __bf16* __restrict__ outpk) {
  __shared__ float sT[32 * 132];
  __shared__ float s_m[32], s_r[32];
  int tid = threadIdx.x, lane = tid & 63, wave = tid >> 6;
  int mtile = blockIdx.x * 2 + wave;
  floatx4 acc[8];
#pragma unroll
  for (int nt = 0; nt < 8; ++nt) acc[nt] = 0;
#pragma unroll
  for (int kc = 0; kc < KCH; ++kc) {
    bf16x8 a;
    if (AF32) {
      const float* ap = (const float*)Ain + (mtile * 16 + (lane & 15)) * (KCH * 32) +
                        kc * 32 + (lane >> 4) * 8;
      float tmp[8];
      *(float4*)tmp = *(const float4*)ap;
      *(float4*)(tmp + 4) = *(const float4*)(ap + 4);
#pragma unroll
      for (int j = 0; j < 8; ++j) a[j] = (__bf16)tmp[j];
    } else {
      a = *((const bf16x8*)Ain + (mtile * KCH + kc) * 64 + lane);
    }
#pragma unroll
    for (int nt = 0; nt < 8; ++nt) {
      bf16x8 b = *((const bf16x8*)Bpk + (nt * KCH + kc) * 64 + lane);
      acc[nt] = __builtin_amdgcn_mfma_f32_16x16x32_bf16(a, b, acc[nt], 0, 0, 0);
    }
  }
  int quad = lane >> 4, cl = lane & 15;
  int rowl = wave * 16 + quad * 4;
#pragma unroll
  for (int nt = 0; nt < 8; ++nt) {
    int col = nt * 16 + cl;
    float bvv = bias[col];
#pragma unroll
    for (int r = 0; r < 4; ++r) sT[(rowl + r) * 132 + col] = acc[nt][r] + bvv;
  }
  __syncthreads();
  {
    int r = tid >> 2, c0 = tid & 3;
    const float* base = sT + r * 132 + c0;
    float s = 0.f, q = 0.f;
#pragma unroll
    for (int k = 0; k < 32; ++k) { float v2 = base[4 * k]; s += v2; q += v2 * v2; }
    s += __shfl_xor(s, 1); s += __shfl_xor(s, 2);
    q += __shfl_xor(q, 1); q += __shfl_xor(q, 2);
    if (c0 == 0) {
      float m = s * (1.f / 128.f);
      s_m[r] = m;
      s_r[r] = rsqrtf(fmaxf(q * (1.f / 128.f) - m * m, 0.f) + EPS);
    }
  }
  __syncthreads();
#pragma unroll
  for (int i = 0; i < 4; ++i) {
    int ch = i * 128 + tid;
    int r = ch >> 4, c8 = (ch & 15) * 8;
    int rowg = blockIdx.x * 32 + r;
    float m = s_m[r], rs = s_r[r];
    float mv = MASKED ? mask[rowg] : 1.f;
    float vals[8];
    *(float4*)vals = *(const float4*)(sT + r * 132 + c8);
    *(float4*)(vals + 4) = *(const float4*)(sT + r * 132 + c8 + 4);
    float4 g0 = *(const float4*)(g + c8), g1 = *(const float4*)(g + c8 + 4);
    float4 b0 = *(const float4*)(be + c8), b1 = *(const float4*)(be + c8 + 4);
    float gg[8] = {g0.x, g0.y, g0.z, g0.w, g1.x, g1.y, g1.z, g1.w};
    float bb[8] = {b0.x, b0.y, b0.z, b0.w, b1.x, b1.y, b1.z, b1.w};
    bf16x8 pk;
#pragma unroll
    for (int k = 0; k < 8; ++k) {
      float val = fmaxf((vals[k] - m) * rs * gg[k] + bb[k], 0.f) * mv;
      vals[k] = val;
      pk[k] = (__bf16)val;
    }
    if (WF32) {
      *(float4*)(outf + rowg * 128 + c8) = *(float4*)vals;
      *(float4*)(outf + rowg * 128 + c8 + 4) = *(float4*)(vals + 4);
    }
    int mtg = rowg >> 4, kc2 = c8 >> 5, q2 = (c8 >> 3) & 3;
    *((bf16x8*)outpk + (mtg * 4 + kc2) * 64 + ((rowg & 15) + (q2 << 4))) = pk;
  }
}

// ---------------------------------------------------------------------------
// fused scores + masked softmax + agg = attn@v, agg written packed-A bf16.
// grid 512 (b, i-chunk of 16) x 256 thr
__global__ __launch_bounds__(256) void score_agg_k(
    const float* __restrict__ hq, const float* __restrict__ hk,
    const float* __restrict__ v, const float* __restrict__ mask,
    const float* __restrict__ We2, const float* __restrict__ be2p,
    __bf16* __restrict__ aggpk) {
  __shared__ float s_hk[64 * 132];
  __shared__ float s_v[64 * 132];
  __shared__ float s_at[16 * 65];
  __shared__ float s_mk[64];
  int tid = threadIdx.x;
  int b = blockIdx.x >> 2, i0 = (blockIdx.x & 3) << 4;
  const float* hkb = hk + b * 64 * 128;
  const float* vb = v + b * 64 * 128;
  for (int idx = tid; idx < 8192; idx += 256) {
    int j = idx >> 7, c = idx & 127;
    s_hk[j * 132 + c] = hkb[idx];
    s_v[j * 132 + c] = vb[idx];
  }
  if (tid < 64) s_mk[tid] = mask[b * 64 + tid];
  __syncthreads();

  int wv = tid >> 6, j = tid & 63;
  float mj = s_mk[j];
  float accs[4] = {};
#pragma unroll
  for (int half = 0; half < 2; ++half) {
    float4 hkv[16], w2v[16];
#pragma unroll
    for (int q = 0; q < 16; ++q) hkv[q] = *(const float4*)(s_hk + j * 132 + half * 64 + q * 4);
#pragma unroll
    for (int q = 0; q < 16; ++q) w2v[q] = *(const float4*)(We2 + half * 64 + q * 4);
#pragma unroll
    for (int k = 0; k < 4; ++k) {
      int il = wv * 4 + k;
      const float4* hq4 = (const float4*)(hq + (b * 64 + i0 + il) * 128 + half * 64);
      float a0 = 0.f;
#pragma unroll
      for (int q = 0; q < 16; ++q) {
        float4 h4 = hq4[q];
        float4 k4 = hkv[q], w4 = w2v[q];
        a0 += fmaxf(h4.x + k4.x, 0.f) * w4.x;
        a0 += fmaxf(h4.y + k4.y, 0.f) * w4.y;
        a0 += fmaxf(h4.z + k4.z, 0.f) * w4.z;
        a0 += fmaxf(h4.w + k4.w, 0.f) * w4.w;
      }
      accs[k] += a0;
    }
  }
  float be2v = be2p[0];
#pragma unroll
  for (int k = 0; k < 4; ++k) {
    int il = wv * 4 + k;
    float m2 = s_mk[i0 + il] * mj;
    float sc = (m2 > 0.f) ? accs[k] + be2v : -1e9f;
    float mx = sc;
#pragma unroll
    for (int off = 32; off >= 1; off >>= 1) mx = fmaxf(mx, __shfl_xor(mx, off));
    float p = __expf(sc - mx);
    float sm = p;
#pragma unroll
    for (int off = 32; off >= 1; off >>= 1) sm += __shfl_xor(sm, off);
    s_at[il * 65 + j] = p / sm * m2;
  }
  __syncthreads();
  // agg: thread (il = tid&15, colgroup cg = tid>>4)
  int il = tid & 15, cg = tid >> 4;
  float4 acc0 = {0, 0, 0, 0}, acc1 = {0, 0, 0, 0};
  const float* vbase = s_v + cg * 8;
#pragma unroll 8
  for (int jj = 0; jj < 64; ++jj) {
    float a = s_at[il * 65 + jj];
    float4 v0 = *(const float4*)(vbase + jj * 132);
    float4 v1 = *(const float4*)(vbase + jj * 132 + 4);
    acc0.x += a * v0.x; acc0.y += a * v0.y; acc0.z += a * v0.z; acc0.w += a * v0.w;
    acc1.x += a * v1.x; acc1.y += a * v1.y; acc1.z += a * v1.z; acc1.w += a * v1.w;
  }
  int rowg = b * 64 + i0 + il;
  int c8 = cg * 8, mtg = rowg >> 4, kc = c8 >> 5, q2 = (c8 >> 3) & 3;
  bf16x8 pk;
  pk[0] = (__bf16)acc0.x; pk[1] = (__bf16)acc0.y; pk[2] = (__bf16)acc0.z; pk[3] = (__bf16)acc0.w;
  pk[4] = (__bf16)acc1.x; pk[5] = (__bf16)acc1.y; pk[6] = (__bf16)acc1.z; pk[7] = (__bf16)acc1.w;
  *((bf16x8*)aggpk + (mtg * 4 + kc) * 64 + ((rowg & 15) + (q2 << 4))) = pk;
}

// ---------------------------------------------------------------------------
// decoder (unchanged from round 1)
__device__ __forceinline__ float ln128(float val, float g, float be, int t, float* red) {
  float s = val, q = val * val;
#pragma unroll
  for (int off = 32; off >= 1; off >>= 1) {
    s += __shfl_xor(s, off);
    q += __shfl_xor(q, off);
  }
  if ((t & 63) == 0) { red[(t >> 6) * 2] = s; red[(t >> 6) * 2 + 1] = q; }
  __syncthreads();
  float S = red[0] + red[2], Q = red[1] + red[3];
  __syncthreads();
  float m = S * (1.f / 128.f);
  float var = Q * (1.f / 128.f) - m * m;
  float r = rsqrtf(fmaxf(var, 0.f) + EPS);
  return (val - m) * r * g + be;
}

__global__ __launch_bounds__(128) void dec_kernel(
    const float* __restrict__ bf, const float* __restrict__ x, const float* __restrict__ mask,
    const float* __restrict__ dW1, const float* __restrict__ db1,
    const float* __restrict__ dg1, const float* __restrict__ dB1,
    const float* __restrict__ dW2, const float* __restrict__ db2,
    const float* __restrict__ dg2, const float* __restrict__ dB2,
    const float* __restrict__ dW3, const float* __restrict__ db3,
    float* __restrict__ out) {
  __shared__ float s_d[Fd + Hd + 1];
  __shared__ float s_z[Hd];
  __shared__ float red[4];
  __shared__ float s_mk[Nn];
  int b = blockIdx.x, t = threadIdx.x;
  if (t < Nn) s_mk[t] = mask[b * Nn + t];
  __syncthreads();
  float den = 0.f;
#pragma unroll
  for (int i = 0; i < Nn; ++i) den += s_mk[i];
  den = fmaxf(den, 1.f);
  float pooled = 0.f;
  const float* xb = x + b * Nn * Hd;
  for (int i = 0; i < Nn; ++i) pooled += xb[i * Hd + t];
  pooled /= den;
  if (t < Fd) s_d[t] = bf[b * Fd + t];
  s_d[Fd + t] = pooled;
  __syncthreads();

  float z = db1[t];
  for (int k = 0; k < Fd + Hd; ++k) z = fmaf(s_d[k], dW1[k * Hd + t], z);
  z = ln128(z, dg1[t], dB1[t], t, red);
  z = fmaxf(z, 0.f);
  s_z[t] = z;
  __syncthreads();

  float z2 = db2[t];
  for (int k = 0; k < Hd; ++k) z2 = fmaf(s_z[k], dW2[k * Hd + t], z2);
  z2 = ln128(z2, dg2[t], dB2[t], t, red);
  z2 = fmaxf(z2, 0.f);
  s_z[t] = z2;
  __syncthreads();

  if (t < Fd) {
    float o = db3[t];
    for (int k = 0; k < Hd; ++k) o = fmaf(s_z[k], dW3[k * Fd + t], o);
    out[b * Fd + t] = o;
  }
}

// ---------------------------------------------------------------------------

extern "C" void kernel_launch(void* const* d_in, const int* in_sizes, int n_in,
                              void* d_out, int out_size, void* d_ws, size_t ws_size,
                              hipStream_t stream) {
  const float* bf   = (const float*)d_in[0];
  const float* emb  = (const float*)d_in[1];
  const float* mask = (const float*)d_in[2];
  const float* eW1 = (const float*)d_in[3];
  const float* eb1 = (const float*)d_in[4];
  const float* eg1 = (const float*)d_in[5];
  const float* eB1 = (const float*)d_in[6];
  const float* eW2 = (const float*)d_in[7];
  const float* eb2 = (const float*)d_in[8];
  const float* eg2 = (const float*)d_in[9];
  const float* eB2 = (const float*)d_in[10];
  const float* Wq = (const float*)d_in[11];
  const float* bq = (const float*)d_in[12];
  const float* Wk = (const float*)d_in[13];
  const float* bk = (const float*)d_in[14];
  const float* Wv = (const float*)d_in[15];
  const float* bv = (const float*)d_in[16];
  const float* We1 = (const float*)d_in[17];
  const float* be1 = (const float*)d_in[18];
  const float* We2 = (const float*)d_in[19];
  const float* be2 = (const float*)d_in[20];
  const float* Wo = (const float*)d_in[21];
  const float* bo = (const float*)d_in[22];
  const float* og = (const float*)d_in[23];
  const float* oB = (const float*)d_in[24];
  const float* dW1 = (const float*)d_in[25];
  const float* db1 = (const float*)d_in[26];
  const float* dg1 = (const float*)d_in[27];
  const float* dB1 = (const float*)d_in[28];
  const float* dW2 = (const float*)d_in[29];
  const float* db2 = (const float*)d_in[30];
  const float* dg2 = (const float*)d_in[31];
  const float* dB2 = (const float*)d_in[32];
  const float* dW3 = (const float*)d_in[33];
  const float* db3 = (const float*)d_in[34];
  float* out = (float*)d_out;

  float* ws = (float*)d_ws;
  float* x     = ws;                    // 1,048,576 f32
  float* vv    = ws + 1048576;          // 1,048,576
  float* hqv   = ws + 2 * 1048576;      // 1,048,576
  float* hkv   = ws + 3 * 1048576;      // 1,048,576
  float* folds = ws + 4 * 1048576;      // 6*16384 = 98,304
  float* bcat  = folds + 98304;         // 3*384 = 1,152
  __bf16* pkb   = (__bf16*)(bcat + 1152);
  __bf16* x_pk  = pkb;                  // 1,048,576 bf16
  __bf16* h_pk  = pkb + 1048576;        // 1,048,576 (aliased with agg_pk; disjoint lifetimes)
  __bf16* aggpk = h_pk;
  __bf16* wcatpk = pkb + 2 * 1048576;   // 3*49,152
  __bf16* wopk   = wcatpk + 147456;     // 3*16,384
  __bf16* w1pk   = wopk + 49152;        // 8,192
  __bf16* w2pk   = w1pk + 8192;         // 16,384

  fold_kernel<<<49, 256, 0, stream>>>(Wq, bq, Wk, bk, bv, We1, be1, folds, bcat);
  pack_kernel<<<14, 256, 0, stream>>>(eW1, eW2, Wv, Wo, folds, w1pk, w2pk, wcatpk, wopk);

  // encoder
  gemm_ln_k<2, true, false, false><<<256, 128, 0, stream>>>(
      emb, w1pk, eb1, eg1, eB1, nullptr, nullptr, h_pk);
  gemm_ln_k<4, false, true, true><<<256, 128, 0, stream>>>(
      h_pk, w2pk, eb2, eg2, eB2, mask, x, x_pk);

  for (int l = 0; l < 3; ++l) {
    gemm_qkv<<<dim3(256, 3), 128, 0, stream>>>(
        x_pk, wcatpk + l * 49152, bcat + l * 384, vv, hqv, hkv);
    score_agg_k<<<512, 256, 0, stream>>>(
        hqv, hkv, vv, mask, We2 + l * 128, be2 + l, aggpk);
    gemm_ln_k<4, false, true, true><<<256, 128, 0, stream>>>(
        aggpk, wopk + l * 16384, bo + l * 128, og + l * 128, oB + l * 128, mask, x, x_pk);
  }
  dec_kernel<<<128, 128, 0, stream>>>(bf, x, mask, dW1, db1, dg1, dB1,
                                      dW2, db2, dg2, dB2, dW3, db3, out);
}

// Round 3
// 223.430 us; speedup vs baseline: 1.7985x; 1.2367x over previous
//
#include <hip/hip_runtime.h>

// MaskedGNN on MI355X — round 3: 6-launch fused pipeline.
// H=128, N=64, B=128, L=3, F=7, E=64.
// All dense GEMMs via mfma_f32_16x16x32_bf16 with pre-packed fragments:
//   A-frag: lane holds A[m=lane&15][k=(lane>>4)*8+j]
//   B-frag: lane holds B[k=(lane>>4)*8+j][n=lane&15]
//   C/D:    col=lane&15, row=(lane>>4)*4+reg

constexpr float EPS = 1e-5f;
constexpr float NEGI = -1e9f;

typedef __bf16 bf16x8 __attribute__((ext_vector_type(8)));
typedef float floatx4 __attribute__((ext_vector_type(4)));

__device__ __forceinline__ bf16x8 cvt8(const float* p) {
  float t[8];
  *(float4*)t = *(const float4*)p;
  *(float4*)(t + 4) = *(const float4*)(p + 4);
  bf16x8 r;
#pragma unroll
  for (int j = 0; j < 8; ++j) r[j] = (__bf16)t[j];
  return r;
}

// ---------------------------------------------------------------------------
// prep: blocks 0..47 fold Wqe/Wke -> wcatpk (nt 8..23); 48..55 pack plain
// weights; 56 bcat = {bv, bq@We1a, bk@We1b+be1}.
__global__ __launch_bounds__(256) void prep_kernel(
    const float* __restrict__ Wq, const float* __restrict__ bq,
    const float* __restrict__ Wk, const float* __restrict__ bk,
    const float* __restrict__ bv, const float* __restrict__ We1,
    const float* __restrict__ be1,
    const float* __restrict__ eW1, const float* __restrict__ eW2,
    const float* __restrict__ Wv, const float* __restrict__ Wo,
    __bf16* __restrict__ w1pk, __bf16* __restrict__ w2pk,
    __bf16* __restrict__ wcatpk, __bf16* __restrict__ wopk,
    float* __restrict__ bcat) {
  int tid = threadIdx.x, blk = blockIdx.x;
  if (blk < 48) {
    __shared__ float sB[128 * 16];
    __shared__ float sF[128 * 17];
    int jb = blk >> 3, cc = blk & 7;
    int l = jb >> 1, w = jb & 1;
    const float* A = (w ? Wk : Wq) + l * 16384;
    const float* Bm = We1 + l * 32768 + w * 16384;
    int c0 = cc * 16;
    for (int idx = tid; idx < 2048; idx += 256) {
      int m = idx >> 4, c = idx & 15;
      sB[idx] = Bm[m * 128 + c0 + c];
    }
    __syncthreads();
    int r = tid >> 1, c8 = (tid & 1) * 8;
    float acc[8] = {};
    const float4* A4 = (const float4*)(A + r * 128);
#pragma unroll 8
    for (int k4 = 0; k4 < 32; ++k4) {
      float4 a = A4[k4];
      float av[4] = {a.x, a.y, a.z, a.w};
#pragma unroll
      for (int kk = 0; kk < 4; ++kk)
#pragma unroll
        for (int c = 0; c < 8; ++c)
          acc[c] = fmaf(av[kk], sB[(k4 * 4 + kk) * 16 + c8 + c], acc[c]);
    }
    for (int c = 0; c < 8; ++c) sF[r * 17 + c8 + c] = acc[c];
    __syncthreads();
    int kc = tid >> 6, lane = tid & 63;
    int k0 = kc * 32 + (lane >> 4) * 8, n = lane & 15;
    bf16x8 pk;
#pragma unroll
    for (int j = 0; j < 8; ++j) pk[j] = (__bf16)sF[(k0 + j) * 17 + n];
    int ntg = 8 + w * 8 + cc;
    *((bf16x8*)(wcatpk + l * 49152) + (ntg * 4 + kc) * 64 + lane) = pk;
  } else if (blk < 56) {
    int job = blk - 48;
    const float* src;
    __bf16* dst;
    int KCH = 4;
    if (job == 0) { src = eW1; dst = w1pk; KCH = 2; }
    else if (job == 1) { src = eW2; dst = w2pk; }
    else if (job < 5) { int l = job - 2; src = Wv + l * 16384; dst = wcatpk + l * 49152; }
    else { int l = job - 5; src = Wo + l * 16384; dst = wopk + l * 16384; }
    for (int s = tid; s < 8 * KCH * 64; s += 256) {
      int lane = s & 63, q = s >> 6;
      int kc = q % KCH, nt = q / KCH;
      int k0 = kc * 32 + (lane >> 4) * 8, n = nt * 16 + (lane & 15);
      bf16x8 pk;
#pragma unroll
      for (int j = 0; j < 8; ++j) pk[j] = (__bf16)src[(k0 + j) * 128 + n];
      *((bf16x8*)dst + (nt * KCH + kc) * 64 + lane) = pk;
    }
  } else {
    for (int idx = tid; idx < 3 * 384; idx += 256) {
      int l = idx / 384, c = idx % 384;
      float val;
      if (c < 128) {
        val = bv[l * 128 + c];
      } else if (c < 256) {
        int cc = c - 128;
        float s = 0.f;
        for (int k = 0; k < 128; ++k) s += bq[l * 128 + k] * We1[l * 32768 + k * 128 + cc];
        val = s;
      } else {
        int cc = c - 256;
        float s = be1[l * 128 + cc];
        for (int k = 0; k < 128; ++k) s += bk[l * 128 + k] * We1[l * 32768 + 16384 + k * 128 + cc];
        val = s;
      }
      bcat[l * 384 + c] = val;
    }
  }
}

// ---------------------------------------------------------------------------
// enc+qkv0: 256 blocks x 256 thr, 32 rows each.
__global__ __launch_bounds__(256) void enc_qkv_kernel(
    const float* __restrict__ emb, const float* __restrict__ mask,
    const float* __restrict__ eb1, const float* __restrict__ eg1, const float* __restrict__ eB1,
    const float* __restrict__ eb2, const float* __restrict__ eg2, const float* __restrict__ eB2,
    const __bf16* __restrict__ w1pk, const __bf16* __restrict__ w2pk,
    const __bf16* __restrict__ wcat0, const float* __restrict__ bcat0,
    float* __restrict__ hq, float* __restrict__ hk, __bf16* __restrict__ vpk) {
  __shared__ float s_T[32 * 132];
  __shared__ __bf16 s_xpk[32 * 128];
  __shared__ float s_m[32], s_r[32];
  int tid = threadIdx.x, lane = tid & 63, wv = tid >> 6;
  int r0 = blockIdx.x * 32;
  int b = blockIdx.x >> 1, kcv = blockIdx.x & 1;
  int cl = lane & 15, quad = lane >> 4;
  int mt = wv & 1, ntb = (wv >> 1) * 4;

  // --- E1 (K=64) ---
  {
    bf16x8 a1[2];
#pragma unroll
    for (int kc = 0; kc < 2; ++kc)
      a1[kc] = cvt8(emb + (r0 + mt * 16 + cl) * 64 + kc * 32 + quad * 8);
    floatx4 acc[4];
#pragma unroll
    for (int n = 0; n < 4; ++n) acc[n] = 0;
#pragma unroll
    for (int kc = 0; kc < 2; ++kc)
#pragma unroll
      for (int n = 0; n < 4; ++n) {
        bf16x8 bfr = *((const bf16x8*)w1pk + ((ntb + n) * 2 + kc) * 64 + lane);
        acc[n] = __builtin_amdgcn_mfma_f32_16x16x32_bf16(a1[kc], bfr, acc[n], 0, 0, 0);
      }
#pragma unroll
    for (int n = 0; n < 4; ++n) {
      int col = (ntb + n) * 16 + cl;
      float bb = eb1[col];
#pragma unroll
      for (int r = 0; r < 4; ++r) s_T[(mt * 16 + quad * 4 + r) * 132 + col] = acc[n][r] + bb;
    }
  }
  __syncthreads();
  // LN (32 rows, 8 thr/row)
  {
    int r = tid >> 3, c0 = tid & 7;
    const float* p = s_T + r * 132 + c0;
    float s = 0.f, q = 0.f;
#pragma unroll
    for (int k = 0; k < 16; ++k) { float v = p[k * 8]; s += v; q += v * v; }
    s += __shfl_xor(s, 1); s += __shfl_xor(s, 2); s += __shfl_xor(s, 4);
    q += __shfl_xor(q, 1); q += __shfl_xor(q, 2); q += __shfl_xor(q, 4);
    if (c0 == 0) {
      float m = s * (1.f / 128.f);
      s_m[r] = m;
      s_r[r] = rsqrtf(fmaxf(q * (1.f / 128.f) - m * m, 0.f) + EPS);
    }
  }
  __syncthreads();
  for (int ch = tid; ch < 512; ch += 256) {
    int r = ch >> 4, c8 = (ch & 15) * 8;
    float vals[8];
    *(float4*)vals = *(const float4*)(s_T + r * 132 + c8);
    *(float4*)(vals + 4) = *(const float4*)(s_T + r * 132 + c8 + 4);
    float m = s_m[r], rs = s_r[r];
    bf16x8 pk;
#pragma unroll
    for (int k = 0; k < 8; ++k)
      pk[k] = (__bf16)fmaxf((vals[k] - m) * rs * eg1[c8 + k] + eB1[c8 + k], 0.f);
    *((bf16x8*)s_xpk + ((r >> 4) * 4 + (c8 >> 5)) * 64 + (((c8 >> 3) & 3) * 16 + (r & 15))) = pk;
  }
  __syncthreads();
  // --- E2 (K=128) ---
  {
    floatx4 acc[4];
#pragma unroll
    for (int n = 0; n < 4; ++n) acc[n] = 0;
    bf16x8 a2[4];
#pragma unroll
    for (int kc = 0; kc < 4; ++kc) a2[kc] = *((const bf16x8*)s_xpk + (mt * 4 + kc) * 64 + lane);
#pragma unroll
    for (int kc = 0; kc < 4; ++kc)
#pragma unroll
      for (int n = 0; n < 4; ++n) {
        bf16x8 bfr = *((const bf16x8*)w2pk + ((ntb + n) * 4 + kc) * 64 + lane);
        acc[n] = __builtin_amdgcn_mfma_f32_16x16x32_bf16(a2[kc], bfr, acc[n], 0, 0, 0);
      }
    __syncthreads();
#pragma unroll
    for (int n = 0; n < 4; ++n) {
      int col = (ntb + n) * 16 + cl;
      float bb = eb2[col];
#pragma unroll
      for (int r = 0; r < 4; ++r) s_T[(mt * 16 + quad * 4 + r) * 132 + col] = acc[n][r] + bb;
    }
  }
  __syncthreads();
  {
    int r = tid >> 3, c0 = tid & 7;
    const float* p = s_T + r * 132 + c0;
    float s = 0.f, q = 0.f;
#pragma unroll
    for (int k = 0; k < 16; ++k) { float v = p[k * 8]; s += v; q += v * v; }
    s += __shfl_xor(s, 1); s += __shfl_xor(s, 2); s += __shfl_xor(s, 4);
    q += __shfl_xor(q, 1); q += __shfl_xor(q, 2); q += __shfl_xor(q, 4);
    if (c0 == 0) {
      float m = s * (1.f / 128.f);
      s_m[r] = m;
      s_r[r] = rsqrtf(fmaxf(q * (1.f / 128.f) - m * m, 0.f) + EPS);
    }
  }
  __syncthreads();
  for (int ch = tid; ch < 512; ch += 256) {
    int r = ch >> 4, c8 = (ch & 15) * 8;
    float vals[8];
    *(float4*)vals = *(const float4*)(s_T + r * 132 + c8);
    *(float4*)(vals + 4) = *(const float4*)(s_T + r * 132 + c8 + 4);
    float m = s_m[r], rs = s_r[r], mk = mask[r0 + r];
    bf16x8 pk;
#pragma unroll
    for (int k = 0; k < 8; ++k)
      pk[k] = (__bf16)(fmaxf((vals[k] - m) * rs * eg2[c8 + k] + eB2[c8 + k], 0.f) * mk);
    *((bf16x8*)s_xpk + ((r >> 4) * 4 + (c8 >> 5)) * 64 + (((c8 >> 3) & 3) * 16 + (r & 15))) = pk;
  }
  __syncthreads();
  // --- qkv0 (N=384) ---
  {
    int ntq = (wv >> 1) * 12;
    bf16x8 aq[4];
#pragma unroll
    for (int kc = 0; kc < 4; ++kc) aq[kc] = *((const bf16x8*)s_xpk + (mt * 4 + kc) * 64 + lane);
    floatx4 acc[12];
#pragma unroll
    for (int n = 0; n < 12; ++n) acc[n] = 0;
#pragma unroll
    for (int kc = 0; kc < 4; ++kc)
#pragma unroll
      for (int n = 0; n < 12; ++n) {
        bf16x8 bfr = *((const bf16x8*)wcat0 + ((ntq + n) * 4 + kc) * 64 + lane);
        acc[n] = __builtin_amdgcn_mfma_f32_16x16x32_bf16(aq[kc], bfr, acc[n], 0, 0, 0);
      }
#pragma unroll
    for (int n = 0; n < 12; ++n) {
      int nt = ntq + n;
      if (nt < 8) {
        int col = nt * 16 + cl;
        float bb = bcat0[col];
#pragma unroll
        for (int r = 0; r < 4; ++r) s_T[(mt * 16 + quad * 4 + r) * 132 + col] = acc[n][r] + bb;
      } else if (nt < 16) {
        int col = (nt - 8) * 16 + cl;
        float bb = bcat0[128 + col];
#pragma unroll
        for (int r = 0; r < 4; ++r) hq[(r0 + mt * 16 + quad * 4 + r) * 128 + col] = acc[n][r] + bb;
      } else {
        int col = (nt - 16) * 16 + cl;
        float bb = bcat0[256 + col];
#pragma unroll
        for (int r = 0; r < 4; ++r) hk[(r0 + mt * 16 + quad * 4 + r) * 128 + col] = acc[n][r] + bb;
      }
    }
  }
  __syncthreads();
  for (int s = tid; s < 512; s += 256) {
    int lane2 = s & 63, nt = s >> 6;
    int q2 = lane2 >> 4, c2 = lane2 & 15;
    bf16x8 pk;
#pragma unroll
    for (int jj = 0; jj < 8; ++jj) pk[jj] = (__bf16)s_T[(q2 * 8 + jj) * 132 + nt * 16 + c2];
    ((bf16x8*)(vpk + b * 8192))[(nt * 2 + kcv) * 64 + lane2] = pk;
  }
}

// ---------------------------------------------------------------------------
// layer: 512 blocks = (b, 16-row quarter) x 256 thr.
template <bool LAST>
__global__ __launch_bounds__(256) void layer_kernel(
    const float* __restrict__ hq_in, const float* __restrict__ hk_in,
    const __bf16* __restrict__ vpk_in, const float* __restrict__ mask,
    const float* __restrict__ We2, const float* __restrict__ be2p,
    const __bf16* __restrict__ wopk_l, const float* __restrict__ bo_l,
    const float* __restrict__ og_l, const float* __restrict__ oB_l,
    const __bf16* __restrict__ wcat_n, const float* __restrict__ bcat_n,
    float* __restrict__ hq_out, float* __restrict__ hk_out,
    __bf16* __restrict__ vpk_out, float* __restrict__ xout) {
  __shared__ float s_hk[64 * 132];
  __shared__ float s_hq[16 * 132];
  __shared__ float s_at[16 * 68];
  __shared__ float s_agg[16 * 132];
  __shared__ float s_T[16 * 132];
  __shared__ __bf16 s_xpk[16 * 128];
  __shared__ float s_m[16], s_r[16];
  __shared__ float s_mk[64];
  int tid = threadIdx.x, lane = tid & 63, wv = tid >> 6;
  int b = blockIdx.x >> 2, i0 = (blockIdx.x & 3) * 16;
  int cl = lane & 15, quad = lane >> 4;

  {
    const float4* src = (const float4*)(hk_in + b * 8192);
    for (int idx = tid; idx < 2048; idx += 256) {
      int row = idx >> 5, c4 = (idx & 31) * 4;
      *(float4*)(s_hk + row * 132 + c4) = src[idx];
    }
    const float4* srq = (const float4*)(hq_in + (b * 64 + i0) * 128);
    for (int idx = tid; idx < 512; idx += 256) {
      int row = idx >> 5, c4 = (idx & 31) * 4;
      *(float4*)(s_hq + row * 132 + c4) = srq[idx];
    }
    if (tid < 64) s_mk[tid] = mask[b * 64 + tid];
  }
  __syncthreads();

  // scores + softmax
  {
    int j = lane;
    float mj = s_mk[j];
    float accs[4] = {};
#pragma unroll
    for (int half = 0; half < 2; ++half) {
      float4 hkv[16], w2v[16];
#pragma unroll
      for (int q = 0; q < 16; ++q) hkv[q] = *(const float4*)(s_hk + j * 132 + half * 64 + q * 4);
#pragma unroll
      for (int q = 0; q < 16; ++q) w2v[q] = *(const float4*)(We2 + half * 64 + q * 4);
#pragma unroll
      for (int kk = 0; kk < 4; ++kk) {
        int il = wv * 4 + kk;
        const float4* hq4 = (const float4*)(s_hq + il * 132 + half * 64);
        float a0 = 0.f, a1 = 0.f, a2 = 0.f, a3 = 0.f;
#pragma unroll
        for (int q = 0; q < 16; ++q) {
          float4 h4 = hq4[q], k4 = hkv[q], w4 = w2v[q];
          a0 = fmaf(fmaxf(h4.x + k4.x, 0.f), w4.x, a0);
          a1 = fmaf(fmaxf(h4.y + k4.y, 0.f), w4.y, a1);
          a2 = fmaf(fmaxf(h4.z + k4.z, 0.f), w4.z, a2);
          a3 = fmaf(fmaxf(h4.w + k4.w, 0.f), w4.w, a3);
        }
        accs[kk] += (a0 + a1) + (a2 + a3);
      }
    }
    float be2v = be2p[0];
#pragma unroll
    for (int kk = 0; kk < 4; ++kk) {
      int il = wv * 4 + kk;
      float m2 = s_mk[i0 + il] * mj;
      float sc = (m2 > 0.f) ? accs[kk] + be2v : NEGI;
      float mx = sc;
#pragma unroll
      for (int off = 32; off >= 1; off >>= 1) mx = fmaxf(mx, __shfl_xor(mx, off));
      float p = __expf(sc - mx);
      float sm = p;
#pragma unroll
      for (int off = 32; off >= 1; off >>= 1) sm += __shfl_xor(sm, off);
      s_at[il * 68 + j] = p / sm * m2;
    }
  }
  __syncthreads();

  // agg = attn @ v (MFMA, bf16 in / fp32 acc)
  {
    bf16x8 aat[2];
#pragma unroll
    for (int kc = 0; kc < 2; ++kc) aat[kc] = cvt8(s_at + cl * 68 + kc * 32 + quad * 8);
    const bf16x8* vb = (const bf16x8*)(vpk_in + b * 8192);
    floatx4 acc[2];
    acc[0] = 0; acc[1] = 0;
#pragma unroll
    for (int kc = 0; kc < 2; ++kc)
#pragma unroll
      for (int n = 0; n < 2; ++n) {
        bf16x8 bfr = vb[((2 * wv + n) * 2 + kc) * 64 + lane];
        acc[n] = __builtin_amdgcn_mfma_f32_16x16x32_bf16(aat[kc], bfr, acc[n], 0, 0, 0);
      }
#pragma unroll
    for (int n = 0; n < 2; ++n) {
      int col = (2 * wv + n) * 16 + cl;
#pragma unroll
      for (int r = 0; r < 4; ++r) s_agg[(quad * 4 + r) * 132 + col] = acc[n][r];
    }
  }
  __syncthreads();

  // Wo GEMM
  {
    bf16x8 ag[4];
#pragma unroll
    for (int kc = 0; kc < 4; ++kc) ag[kc] = cvt8(s_agg + cl * 132 + kc * 32 + quad * 8);
    floatx4 acc[2];
    acc[0] = 0; acc[1] = 0;
#pragma unroll
    for (int kc = 0; kc < 4; ++kc)
#pragma unroll
      for (int n = 0; n < 2; ++n) {
        bf16x8 bfr = *((const bf16x8*)wopk_l + ((2 * wv + n) * 4 + kc) * 64 + lane);
        acc[n] = __builtin_amdgcn_mfma_f32_16x16x32_bf16(ag[kc], bfr, acc[n], 0, 0, 0);
      }
#pragma unroll
    for (int n = 0; n < 2; ++n) {
      int col = (2 * wv + n) * 16 + cl;
      float bb = bo_l[col];
#pragma unroll
      for (int r = 0; r < 4; ++r) s_T[(quad * 4 + r) * 132 + col] = acc[n][r] + bb;
    }
  }
  __syncthreads();

  // LN (16 rows, 16 thr/row)
  {
    int r = tid >> 4, c0 = tid & 15;
    const float* p = s_T + r * 132 + c0;
    float s = 0.f, q = 0.f;
#pragma unroll
    for (int k = 0; k < 8; ++k) { float v = p[k * 16]; s += v; q += v * v; }
    s += __shfl_xor(s, 1); s += __shfl_xor(s, 2); s += __shfl_xor(s, 4); s += __shfl_xor(s, 8);
    q += __shfl_xor(q, 1); q += __shfl_xor(q, 2); q += __shfl_xor(q, 4); q += __shfl_xor(q, 8);
    if (c0 == 0) {
      float m = s * (1.f / 128.f);
      s_m[r] = m;
      s_r[r] = rsqrtf(fmaxf(q * (1.f / 128.f) - m * m, 0.f) + EPS);
    }
  }
  __syncthreads();
  {
    int r = tid >> 4, c8 = (tid & 15) * 8;
    float vals[8];
    *(float4*)vals = *(const float4*)(s_T + r * 132 + c8);
    *(float4*)(vals + 4) = *(const float4*)(s_T + r * 132 + c8 + 4);
    float m = s_m[r], rs = s_r[r], mk = s_mk[i0 + r];
#pragma unroll
    for (int k = 0; k < 8; ++k)
      vals[k] = fmaxf((vals[k] - m) * rs * og_l[c8 + k] + oB_l[c8 + k], 0.f) * mk;
    if (LAST) {
      float* xp = xout + (b * 64 + i0 + r) * 128 + c8;
      *(float4*)xp = *(float4*)vals;
      *(float4*)(xp + 4) = *(float4*)(vals + 4);
    } else {
      bf16x8 pk;
#pragma unroll
      for (int k = 0; k < 8; ++k) pk[k] = (__bf16)vals[k];
      *((bf16x8*)s_xpk + (c8 >> 5) * 64 + (((c8 >> 3) & 3) * 16 + r)) = pk;
    }
  }
  if (!LAST) {
    __syncthreads();
    // qkv(l+1): wave covers nt = wv*6 .. wv*6+5
    {
      bf16x8 ax[4];
#pragma unroll
      for (int kc = 0; kc < 4; ++kc) ax[kc] = *((const bf16x8*)s_xpk + kc * 64 + lane);
      floatx4 acc[6];
#pragma unroll
      for (int n = 0; n < 6; ++n) acc[n] = 0;
#pragma unroll
      for (int kc = 0; kc < 4; ++kc)
#pragma unroll
        for (int n = 0; n < 6; ++n) {
          bf16x8 bfr = *((const bf16x8*)wcat_n + ((wv * 6 + n) * 4 + kc) * 64 + lane);
          acc[n] = __builtin_amdgcn_mfma_f32_16x16x32_bf16(ax[kc], bfr, acc[n], 0, 0, 0);
        }
#pragma unroll
      for (int n = 0; n < 6; ++n) {
        int nt = wv * 6 + n;
        if (nt < 8) {
          int col = nt * 16 + cl;
          float bb = bcat_n[col];
#pragma unroll
          for (int r = 0; r < 4; ++r) s_T[(quad * 4 + r) * 132 + col] = acc[n][r] + bb;
        } else if (nt < 16) {
          int col = (nt - 8) * 16 + cl;
          float bb = bcat_n[128 + col];
#pragma unroll
          for (int r = 0; r < 4; ++r) hq_out[(b * 64 + i0 + quad * 4 + r) * 128 + col] = acc[n][r] + bb;
        } else {
          int col = (nt - 16) * 16 + cl;
          float bb = bcat_n[256 + col];
#pragma unroll
          for (int r = 0; r < 4; ++r) hk_out[(b * 64 + i0 + quad * 4 + r) * 128 + col] = acc[n][r] + bb;
        }
      }
    }
    __syncthreads();
    // pack v slice (this block owns j rows [i0, i0+16))
    {
      int kcv = i0 >> 5, q0 = (i0 & 31) >> 3;
      int nt = tid >> 5, dq = (tid >> 4) & 1, c2 = tid & 15;
      int qg = q0 + dq;
      bf16x8 pk;
#pragma unroll
      for (int jj = 0; jj < 8; ++jj) pk[jj] = (__bf16)s_T[(dq * 8 + jj) * 132 + nt * 16 + c2];
      ((bf16x8*)(vpk_out + b * 8192))[(nt * 2 + kcv) * 64 + qg * 16 + c2] = pk;
    }
  }
}

// ---------------------------------------------------------------------------
__device__ __forceinline__ float ln128(float val, float g, float be, int t, float* red) {
  float s = val, q = val * val;
#pragma unroll
  for (int off = 32; off >= 1; off >>= 1) {
    s += __shfl_xor(s, off);
    q += __shfl_xor(q, off);
  }
  if ((t & 63) == 0) { red[(t >> 6) * 2] = s; red[(t >> 6) * 2 + 1] = q; }
  __syncthreads();
  float S = red[0] + red[2], Q = red[1] + red[3];
  __syncthreads();
  float m = S * (1.f / 128.f);
  float var = Q * (1.f / 128.f) - m * m;
  float r = rsqrtf(fmaxf(var, 0.f) + EPS);
  return (val - m) * r * g + be;
}

__global__ __launch_bounds__(128) void dec_kernel(
    const float* __restrict__ bf, const float* __restrict__ x, const float* __restrict__ mask,
    const float* __restrict__ dW1, const float* __restrict__ db1,
    const float* __restrict__ dg1, const float* __restrict__ dB1,
    const float* __restrict__ dW2, const float* __restrict__ db2,
    const float* __restrict__ dg2, const float* __restrict__ dB2,
    const float* __restrict__ dW3, const float* __restrict__ db3,
    float* __restrict__ out) {
  __shared__ float s_d[136];
  __shared__ float s_z[128];
  __shared__ float red[4];
  __shared__ float s_mk[64];
  int b = blockIdx.x, t = threadIdx.x;
  if (t < 64) s_mk[t] = mask[b * 64 + t];
  __syncthreads();
  float den = 0.f;
#pragma unroll
  for (int i = 0; i < 64; ++i) den += s_mk[i];
  den = fmaxf(den, 1.f);
  float pooled = 0.f;
  const float* xb = x + b * 8192;
  for (int i = 0; i < 64; ++i) pooled += xb[i * 128 + t];
  pooled /= den;
  if (t < 7) s_d[t] = bf[b * 7 + t];
  s_d[7 + t] = pooled;
  __syncthreads();

  float z = db1[t];
  for (int k = 0; k < 135; ++k) z = fmaf(s_d[k], dW1[k * 128 + t], z);
  z = ln128(z, dg1[t], dB1[t], t, red);
  z = fmaxf(z, 0.f);
  s_z[t] = z;
  __syncthreads();

  float z2 = db2[t];
  for (int k = 0; k < 128; ++k) z2 = fmaf(s_z[k], dW2[k * 128 + t], z2);
  z2 = ln128(z2, dg2[t], dB2[t], t, red);
  z2 = fmaxf(z2, 0.f);
  s_z[t] = z2;
  __syncthreads();

  if (t < 7) {
    float o = db3[t];
    for (int k = 0; k < 128; ++k) o = fmaf(s_z[k], dW3[k * 7 + t], o);
    out[b * 7 + t] = o;
  }
}

// ---------------------------------------------------------------------------
extern "C" void kernel_launch(void* const* d_in, const int* in_sizes, int n_in,
                              void* d_out, int out_size, void* d_ws, size_t ws_size,
                              hipStream_t stream) {
  const float* bf   = (const float*)d_in[0];
  const float* emb  = (const float*)d_in[1];
  const float* mask = (const float*)d_in[2];
  const float* eW1 = (const float*)d_in[3];
  const float* eb1 = (const float*)d_in[4];
  const float* eg1 = (const float*)d_in[5];
  const float* eB1 = (const float*)d_in[6];
  const float* eW2 = (const float*)d_in[7];
  const float* eb2 = (const float*)d_in[8];
  const float* eg2 = (const float*)d_in[9];
  const float* eB2 = (const float*)d_in[10];
  const float* Wq = (const float*)d_in[11];
  const float* bq = (const float*)d_in[12];
  const float* Wk = (const float*)d_in[13];
  const float* bk = (const float*)d_in[14];
  const float* Wv = (const float*)d_in[15];
  const float* bv = (const float*)d_in[16];
  const float* We1 = (const float*)d_in[17];
  const float* be1 = (const float*)d_in[18];
  const float* We2 = (const float*)d_in[19];
  const float* be2 = (const float*)d_in[20];
  const float* Wo = (const float*)d_in[21];
  const float* bo = (const float*)d_in[22];
  const float* og = (const float*)d_in[23];
  const float* oB = (const float*)d_in[24];
  const float* dW1 = (const float*)d_in[25];
  const float* db1 = (const float*)d_in[26];
  const float* dg1 = (const float*)d_in[27];
  const float* dB1 = (const float*)d_in[28];
  const float* dW2 = (const float*)d_in[29];
  const float* db2 = (const float*)d_in[30];
  const float* dg2 = (const float*)d_in[31];
  const float* dB2 = (const float*)d_in[32];
  const float* dW3 = (const float*)d_in[33];
  const float* db3 = (const float*)d_in[34];
  float* out = (float*)d_out;

  float* ws = (float*)d_ws;
  float* hqA  = ws;
  float* hkA  = ws + 1048576;
  float* hqB  = ws + 2 * 1048576;
  float* hkB  = ws + 3 * 1048576;
  float* x    = ws + 4 * 1048576;
  float* bcat = ws + 5 * 1048576;          // 1152
  __bf16* bb16  = (__bf16*)(ws + 5 * 1048576 + 2048);
  __bf16* vpkA  = bb16;                    // 1,048,576 bf16
  __bf16* vpkB  = bb16 + 1048576;
  __bf16* wcatpk = bb16 + 2 * 1048576;     // 3*49152
  __bf16* wopk   = wcatpk + 3 * 49152;     // 3*16384
  __bf16* w1pk   = wopk + 3 * 16384;       // 8192
  __bf16* w2pk   = w1pk + 8192;            // 16384

  prep_kernel<<<57, 256, 0, stream>>>(Wq, bq, Wk, bk, bv, We1, be1,
                                      eW1, eW2, Wv, Wo, w1pk, w2pk, wcatpk, wopk, bcat);
  enc_qkv_kernel<<<256, 256, 0, stream>>>(emb, mask, eb1, eg1, eB1, eb2, eg2, eB2,
                                          w1pk, w2pk, wcatpk, bcat, hqA, hkA, vpkA);
  layer_kernel<false><<<512, 256, 0, stream>>>(
      hqA, hkA, vpkA, mask, We2, be2, wopk, bo, og, oB,
      wcatpk + 49152, bcat + 384, hqB, hkB, vpkB, nullptr);
  layer_kernel<false><<<512, 256, 0, stream>>>(
      hqB, hkB, vpkB, mask, We2 + 128, be2 + 1, wopk + 16384, bo + 128, og + 128, oB + 128,
      wcatpk + 2 * 49152, bcat + 2 * 384, hqA, hkA, vpkA, nullptr);
  layer_kernel<true><<<512, 256, 0, stream>>>(
      hqA, hkA, vpkA, mask, We2 + 256, be2 + 2, wopk + 2 * 16384, bo + 256, og + 256, oB + 256,
      nullptr, nullptr, nullptr, nullptr, nullptr, x);
  dec_kernel<<<128, 128, 0, stream>>>(bf, x, mask, dW1, db1, dg1, dB1,
                                      dW2, db2, dg2, dB2, dW3, db3, out);
}